// Round 10
// baseline (41802.176 us; speedup 1.0000x reference)
//
#include <hip/hip_runtime.h>
#include <math.h>

#define DD    1024
#define BB    128
#define G3    3072
#define VOUT  8000
#define S_SRC 256
#define S_TGT 128
#define SOS   1

typedef unsigned long long u64;

// ---------------------------------------------------------------------------
// argmax packing: p = (fkey(v) << 32) | (0x7FFFFFFF - index); max(p) picks
// (max value, first index on tie). Proven in r8.
// ---------------------------------------------------------------------------
__device__ __forceinline__ unsigned fkey(float f) {
    unsigned b = __float_as_uint(f);
    return (b & 0x80000000u) ? ~b : (b | 0x80000000u);
}
__device__ __forceinline__ int tok_decode(u64 p) {
    return (int)(0x7FFFFFFFu - (unsigned)(p & 0xFFFFFFFFull));
}

__device__ __forceinline__ float gru1(float ir, float iz, float in_,
                                      float hr, float hz, float hn, float hv) {
    float r = 1.0f / (1.0f + expf(-(ir + hr)));
    float z = 1.0f / (1.0f + expf(-(iz + hz)));
    float n = tanhf(in_ + r * hn);
    return (1.0f - z) * n + z * hv;
}

// ---------------------------------------------------------------------------
// init: hb0 = 0 (h_0), amax slot0 = SOS, slots 1..S_TGT = 0
// ---------------------------------------------------------------------------
__global__ __launch_bounds__(256) void k_init(float* __restrict__ h0,
                                              u64* __restrict__ amax) {
    int idx = blockIdx.x * 256 + threadIdx.x;
    if (idx < BB * DD) h0[idx] = 0.0f;
    if (idx < (S_TGT + 1) * BB)
        amax[idx] = (idx < BB) ? (u64)(0x7FFFFFFFu - SOS) : 0ull;
}

// ---------------------------------------------------------------------------
// r1-proven GEMM core: BM=128, BN=32, BK=32, 256 threads, 8x2 micro-tile.
// ---------------------------------------------------------------------------
__device__ __forceinline__ void gemm_core(
    float (* __restrict__ As)[132], float (* __restrict__ Bs)[34],
    const float* __restrict__ A0, const float* __restrict__ A1,
    const float* __restrict__ A2, const float* __restrict__ A3,
    const float* __restrict__ Brow, int kbeg, int ntiles,
    float (&acc)[8][2])
{
    const int tid = threadIdx.x;
    const int kq  = (tid & 7) * 4;
    const int r0  = tid >> 3;
    const int tx  = tid & 15, ty = tid >> 4;
    const float* Arow[4] = {A0, A1, A2, A3};

    for (int t = 0; t < ntiles; ++t) {
        const int k0 = kbeg + t * 32;
        #pragma unroll
        for (int p = 0; p < 4; ++p) {
            float4 v = *reinterpret_cast<const float4*>(Arow[p] + k0 + kq);
            int m = r0 + p * 32;
            As[kq+0][m] = v.x; As[kq+1][m] = v.y; As[kq+2][m] = v.z; As[kq+3][m] = v.w;
        }
        {
            float4 v = *reinterpret_cast<const float4*>(Brow + k0 + kq);
            Bs[kq+0][r0] = v.x; Bs[kq+1][r0] = v.y; Bs[kq+2][r0] = v.z; Bs[kq+3][r0] = v.w;
        }
        __syncthreads();
        #pragma unroll
        for (int k = 0; k < 32; ++k) {
            float a[8];
            #pragma unroll
            for (int i = 0; i < 8; ++i) a[i] = As[k][ty*8 + i];
            float b0 = Bs[k][tx*2 + 0], b1 = Bs[k][tx*2 + 1];
            #pragma unroll
            for (int i = 0; i < 8; ++i) {
                acc[i][0] = fmaf(a[i], b0, acc[i][0]);
                acc[i][1] = fmaf(a[i], b1, acc[i][1]);
            }
        }
        __syncthreads();
    }
}

// ---------------------------------------------------------------------------
// NEW: encoder gates with INLINE deferred update.
// Block (nt = blockIdx.x in 0..95, kh = blockIdx.y in 0..3), K-slice
// [kh*256, (kh+1)*256). Per 32-col k-tile: compute h_s[:, tile] =
// gru(gi_{s-1}, sum(p_prev)+bhh, h_{s-1}) elementwise, stage directly into
// As, (nt==0 also writes h_s to global for the next launch), then the proven
// FMA loop accumulates gh_s = h_s @ Whh-slice. All inputs (h_{s-1}, gi_{s-1},
// p_prev) were written by PREVIOUS launches — cross-kernel dataflow only.
// first=1 (s==0): h_0 = h_prev buffer (zeros), plain staging, no h write.
// ---------------------------------------------------------------------------
__global__ __launch_bounds__(256) void k_enc_gates_iu(
    const float* __restrict__ h_prev, float* __restrict__ h_cur,
    const float* __restrict__ Whh, const float* __restrict__ bhh,
    const float* __restrict__ gi_s, const float* __restrict__ p_prev,
    float* __restrict__ p_cur, int first)
{
    __shared__ float As[32][132];
    __shared__ float Bs[32][34];
    const int nt  = blockIdx.x;
    const int kh  = blockIdx.y;
    const int tid = threadIdx.x;
    const int kq  = (tid & 7) * 4;
    const int r0  = tid >> 3;
    const int tx  = tid & 15, ty = tid >> 4;
    const int kbeg = kh * 256;
    const bool writer = (nt == 0);
    const float* Brow = Whh + (size_t)(nt*32 + r0) * DD;

    float acc[8][2] = {};
    for (int t = 0; t < 8; ++t) {
        const int k0 = kbeg + t * 32;
        const int col = k0 + kq;
        if (first) {
            #pragma unroll
            for (int p = 0; p < 4; ++p) {
                int m = r0 + 32 * p;
                float4 v = *reinterpret_cast<const float4*>(
                    h_prev + (size_t)m * DD + col);
                As[kq+0][m] = v.x; As[kq+1][m] = v.y;
                As[kq+2][m] = v.z; As[kq+3][m] = v.w;
            }
        } else {
            float4 bh0 = *reinterpret_cast<const float4*>(bhh + col);
            float4 bh1 = *reinterpret_cast<const float4*>(bhh + DD + col);
            float4 bh2 = *reinterpret_cast<const float4*>(bhh + 2*DD + col);
            #pragma unroll
            for (int p = 0; p < 4; ++p) {
                int m = r0 + 32 * p;
                float4 hp = *reinterpret_cast<const float4*>(
                    h_prev + (size_t)m * DD + col);
                const float* gim = gi_s + (size_t)m * G3 + col;
                float4 g0 = *reinterpret_cast<const float4*>(gim);
                float4 g1 = *reinterpret_cast<const float4*>(gim + DD);
                float4 g2 = *reinterpret_cast<const float4*>(gim + 2*DD);
                float4 s0 = bh0, s1 = bh1, s2 = bh2;
                #pragma unroll
                for (int q = 0; q < 4; ++q) {
                    const float* pq = p_prev + (size_t)q * (BB * G3)
                                      + (size_t)m * G3 + col;
                    float4 a = *reinterpret_cast<const float4*>(pq);
                    float4 b = *reinterpret_cast<const float4*>(pq + DD);
                    float4 c = *reinterpret_cast<const float4*>(pq + 2*DD);
                    s0.x += a.x; s0.y += a.y; s0.z += a.z; s0.w += a.w;
                    s1.x += b.x; s1.y += b.y; s1.z += b.z; s1.w += b.w;
                    s2.x += c.x; s2.y += c.y; s2.z += c.z; s2.w += c.w;
                }
                float4 hv;
                hv.x = gru1(g0.x, g1.x, g2.x, s0.x, s1.x, s2.x, hp.x);
                hv.y = gru1(g0.y, g1.y, g2.y, s0.y, s1.y, s2.y, hp.y);
                hv.z = gru1(g0.z, g1.z, g2.z, s0.z, s1.z, s2.z, hp.z);
                hv.w = gru1(g0.w, g1.w, g2.w, s0.w, s1.w, s2.w, hp.w);
                As[kq+0][m] = hv.x; As[kq+1][m] = hv.y;
                As[kq+2][m] = hv.z; As[kq+3][m] = hv.w;
                if (writer)
                    *reinterpret_cast<float4*>(h_cur + (size_t)m * DD + col) = hv;
            }
        }
        {
            float4 v = *reinterpret_cast<const float4*>(Brow + k0 + kq);
            Bs[kq+0][r0] = v.x; Bs[kq+1][r0] = v.y;
            Bs[kq+2][r0] = v.z; Bs[kq+3][r0] = v.w;
        }
        __syncthreads();
        #pragma unroll
        for (int k = 0; k < 32; ++k) {
            float a[8];
            #pragma unroll
            for (int i = 0; i < 8; ++i) a[i] = As[k][ty*8 + i];
            float b0 = Bs[k][tx*2 + 0], b1 = Bs[k][tx*2 + 1];
            #pragma unroll
            for (int i = 0; i < 8; ++i) {
                acc[i][0] = fmaf(a[i], b0, acc[i][0]);
                acc[i][1] = fmaf(a[i], b1, acc[i][1]);
            }
        }
        __syncthreads();
    }
    float* C = p_cur + (size_t)kh * (BB * G3);
    #pragma unroll
    for (int i = 0; i < 8; ++i) {
        size_t m = (size_t)(ty*8 + i);
        C[m * G3 + nt*32 + tx*2 + 0] = acc[i][0];
        C[m * G3 + nt*32 + tx*2 + 1] = acc[i][1];
    }
}

// ---------------------------------------------------------------------------
// Encoder input-projection chunk GEMM (r1-proven): grid (96, CH) x 256.
// gi_buf[cs][m][n] = emb[src[m]] . Wih[n] + bih[n]
// ---------------------------------------------------------------------------
__global__ __launch_bounds__(256) void k_gi_chunk(
    const float* __restrict__ emb, const int* __restrict__ src_c,
    const float* __restrict__ Wih, const float* __restrict__ bih,
    float* __restrict__ gi_buf)
{
    __shared__ float As[32][132];
    __shared__ float Bs[32][34];
    const int n0 = blockIdx.x * 32;
    const int cs = blockIdx.y;
    const int tid = threadIdx.x;
    const int r0 = tid >> 3, tx = tid & 15, ty = tid >> 4;

    const int* srow = src_c + cs * BB;
    const float* A[4];
    #pragma unroll
    for (int p = 0; p < 4; ++p)
        A[p] = emb + (size_t)srow[r0 + 32 * p] * DD;
    float acc[8][2] = {};
    gemm_core(As, Bs, A[0], A[1], A[2], A[3],
              Wih + (size_t)(n0 + r0) * DD, 0, DD/32, acc);
    float* C = gi_buf + (size_t)cs * (BB * G3);
    #pragma unroll
    for (int i = 0; i < 8; ++i) {
        int m = ty * 8 + i;
        #pragma unroll
        for (int j = 0; j < 2; ++j) {
            int n = n0 + tx * 2 + j;
            C[(size_t)m * G3 + n] = acc[i][j] + bih[n];
        }
    }
}

// ---------------------------------------------------------------------------
// Decoder split-K gates (r1-proven core, r8-proven amax token decode):
// grid (96, 2, 4): side = blockIdx.y (0: gi from emb[tok], 1: gh from h).
// ---------------------------------------------------------------------------
__global__ __launch_bounds__(256) void k_gates_ks(
    const float* __restrict__ emb, const u64* __restrict__ amax_in,
    const float* __restrict__ h,
    const float* __restrict__ Wih, const float* __restrict__ Whh,
    float* __restrict__ gi_base, float* __restrict__ gh_base)
{
    __shared__ float As[32][132];
    __shared__ float Bs[32][34];
    const int side = blockIdx.y;
    const int kh   = blockIdx.z;
    const float* __restrict__ W = side ? Whh : Wih;
    float* __restrict__ C = (side ? gh_base : gi_base) + (size_t)kh * (BB * G3);
    const int n0 = blockIdx.x * 32;
    const int tid = threadIdx.x;
    const int r0 = tid >> 3, tx = tid & 15, ty = tid >> 4;

    const float* A[4];
    #pragma unroll
    for (int p = 0; p < 4; ++p) {
        int m = r0 + p * 32;
        A[p] = side ? (h + (size_t)m * DD)
                    : (emb + (size_t)tok_decode(amax_in[m]) * DD);
    }
    float acc[8][2] = {};
    gemm_core(As, Bs, A[0], A[1], A[2], A[3],
              W + (size_t)(n0 + r0) * DD, kh * 256, 8, acc);
    #pragma unroll
    for (int i = 0; i < 8; ++i) {
        size_t m = (size_t)(ty*8 + i);
        C[m * G3 + n0 + tx*2 + 0] = acc[i][0];
        C[m * G3 + n0 + tx*2 + 1] = acc[i][1];
    }
}

// ---------------------------------------------------------------------------
// GRU update summing split-K partials + biases (r1-proven). In-place on h.
// ---------------------------------------------------------------------------
__global__ __launch_bounds__(256) void k_update_f(
    const float* __restrict__ gi_base, int ns_i, const float* __restrict__ bih,
    const float* __restrict__ gh_base, int ns_h, const float* __restrict__ bhh,
    float* __restrict__ h)
{
    int idx = blockIdx.x * 256 + threadIdx.x;
    int b = idx >> 10, d = idx & 1023;
    size_t o = (size_t)b * G3 + d;
    float ir = 0.f, iz = 0.f, in_ = 0.f;
    for (int p = 0; p < ns_i; ++p) {
        const float* g = gi_base + (size_t)p * (BB * G3);
        ir += g[o]; iz += g[o + DD]; in_ += g[o + 2*DD];
    }
    if (bih) { ir += bih[d]; iz += bih[DD + d]; in_ += bih[2*DD + d]; }
    float hr = 0.f, hz = 0.f, hn = 0.f;
    for (int p = 0; p < ns_h; ++p) {
        const float* g = gh_base + (size_t)p * (BB * G3);
        hr += g[o]; hz += g[o + DD]; hn += g[o + 2*DD];
    }
    hr += bhh[d]; hz += bhh[DD + d]; hn += bhh[2*DD + d];
    h[idx] = gru1(ir, iz, in_, hr, hz, hn, h[idx]);
}

// ---------------------------------------------------------------------------
// Decoder logits + argmax (r8-proven): 250 blocks x 512 threads, full-K,
// 4x2 micro. Epilogue: bias, out store, 16-lane shfl reduce, atomicMax.
// ---------------------------------------------------------------------------
__global__ __launch_bounds__(512) void k_logits_amax(
    const float* __restrict__ h, const float* __restrict__ outW,
    const float* __restrict__ outb, float* __restrict__ outC,
    u64* __restrict__ amax_out)
{
    __shared__ float As[32][132];
    __shared__ float Bs[32][34];
    const int n0  = blockIdx.x * 32;
    const int tid = threadIdx.x;
    const int kq  = (tid & 7) * 4;
    const int rr  = tid >> 3;
    const int tx  = tid & 15, ty = tid >> 4;

    const float* Brow = (tid < 256)
        ? outW + (size_t)(n0 + (tid >> 3)) * DD : nullptr;

    float acc[4][2] = {};
    for (int k0 = 0; k0 < DD; k0 += 32) {
        if (rr < 64) {
            float4 v = *reinterpret_cast<const float4*>(
                h + (size_t)rr * DD + k0 + kq);
            As[kq+0][rr] = v.x; As[kq+1][rr] = v.y; As[kq+2][rr] = v.z; As[kq+3][rr] = v.w;
            float4 w = *reinterpret_cast<const float4*>(
                h + (size_t)(rr + 64) * DD + k0 + kq);
            As[kq+0][rr+64] = w.x; As[kq+1][rr+64] = w.y;
            As[kq+2][rr+64] = w.z; As[kq+3][rr+64] = w.w;
        }
        if (tid < 256) {
            float4 v = *reinterpret_cast<const float4*>(Brow + k0 + kq);
            int nr = tid >> 3;
            Bs[kq+0][nr] = v.x; Bs[kq+1][nr] = v.y; Bs[kq+2][nr] = v.z; Bs[kq+3][nr] = v.w;
        }
        __syncthreads();
        #pragma unroll
        for (int k = 0; k < 32; ++k) {
            float a[4];
            #pragma unroll
            for (int i = 0; i < 4; ++i) a[i] = As[k][4*ty + i];
            float b0 = Bs[k][2*tx], b1 = Bs[k][2*tx + 1];
            #pragma unroll
            for (int i = 0; i < 4; ++i) {
                acc[i][0] = fmaf(a[i], b0, acc[i][0]);
                acc[i][1] = fmaf(a[i], b1, acc[i][1]);
            }
        }
        __syncthreads();
    }

    const int c0 = n0 + 2 * tx;
    const float b0 = outb[c0], b1 = outb[c0 + 1];
    #pragma unroll
    for (int i = 0; i < 4; ++i) {
        int m = 4 * ty + i;
        float v0 = acc[i][0] + b0, v1 = acc[i][1] + b1;
        float2 st; st.x = v0; st.y = v1;
        *reinterpret_cast<float2*>(outC + (size_t)m * VOUT + c0) = st;
        u64 p0 = ((u64)fkey(v0) << 32) | (u64)(0x7FFFFFFFu - c0);
        u64 p1 = ((u64)fkey(v1) << 32) | (u64)(0x7FFFFFFFu - (c0 + 1));
        u64 p = p0 > p1 ? p0 : p1;
        #pragma unroll
        for (int off = 8; off > 0; off >>= 1) {
            u64 q = __shfl_xor(p, off, 16);
            if (q > p) p = q;
        }
        if (tx == 0) atomicMax(&amax_out[m], p);
    }
}

// ---------------------------------------------------------------------------
extern "C" void kernel_launch(void* const* d_in, const int* in_sizes, int n_in,
                              void* d_out, int out_size, void* d_ws, size_t ws_size,
                              hipStream_t stream) {
    const int*   src     = (const int*)  d_in[0];
    const float* enc_emb = (const float*)d_in[2];
    const float* eWih    = (const float*)d_in[3];
    const float* eWhh    = (const float*)d_in[4];
    const float* ebih    = (const float*)d_in[5];
    const float* ebhh    = (const float*)d_in[6];
    const float* dec_emb = (const float*)d_in[7];
    const float* dWih    = (const float*)d_in[8];
    const float* dWhh    = (const float*)d_in[9];
    const float* dbih    = (const float*)d_in[10];
    const float* dbhh    = (const float*)d_in[11];
    const float* outW    = (const float*)d_in[12];
    const float* outb    = (const float*)d_in[13];
    float* out = (float*)d_out;

    // workspace: hb0/hb1 ping-pong, 8 partial slots, amax, gi chunks
    float* hb0 = (float*)d_ws;                    // 128*1024
    float* hb1 = hb0 + BB * DD;                   // 128*1024
    float* g_p = hb1 + BB * DD;                   // 8 * 128*3072
    u64*  amax = (u64*)(g_p + 8 * BB * G3);       // (S_TGT+1)*128
    float* gi_buf = (float*)(amax + (S_TGT + 1) * BB);

    size_t fixed = (size_t)((char*)gi_buf - (char*)d_ws);
    size_t avail = (ws_size > fixed) ? ws_size - fixed : 0;
    int CH = 8;
    while (CH > 1 && (size_t)CH * BB * G3 * 4 > avail) CH >>= 1;

    k_init<<<512, 256, 0, stream>>>(hb0, amax);

    // ---- Encoder: 1 fused gates+deferred-update launch per step ----
    // gates(s): A = h_s computed inline from (h_{s-1}, gi_{s-1}, partials_{s-1});
    // writes partials_s (pslots[s&1]) and h_s (hb[s&1], nt==0 blocks).
    // chunk(s) (after gates(s), every CH steps) provides gi_s..gi_{s+CH-1}.
    for (int s = 0; s < S_SRC; ++s) {
        const float* hprev = (s == 0) ? hb0 : (((s - 1) & 1) ? hb1 : hb0);
        float*       hcur  = (s & 1) ? hb1 : hb0;
        const float* gi_sP = gi_buf + (size_t)((s > 0 ? s - 1 : 0) % CH) * (BB * G3);
        const float* pprev = g_p + (size_t)((s + 1) & 1) * (4 * BB * G3);
        float*       pcur  = g_p + (size_t)(s & 1) * (4 * BB * G3);
        k_enc_gates_iu<<<dim3(96, 4), 256, 0, stream>>>(
            hprev, hcur, eWhh, ebhh, gi_sP, pprev, pcur, s == 0 ? 1 : 0);
        if ((s % CH) == 0)
            k_gi_chunk<<<dim3(96, CH), 256, 0, stream>>>(
                enc_emb, src + s * BB, eWih, ebih, gi_buf);
    }
    // final update: h_enc = gru(gi_255, partials_255, h_255) in-place in hb1
    k_update_f<<<512, 256, 0, stream>>>(
        gi_buf + (size_t)((S_SRC - 1) % CH) * (BB * G3), 1, nullptr,
        g_p + (size_t)((S_SRC - 1) & 1) * (4 * BB * G3), 4, ebhh, hb1);

    // ---- Decoder: proven 3-launch chain per step (h in-place in hb1) ----
    float* gi_p = g_p;                       // slots 0..3
    float* gh_p = g_p + 4 * BB * G3;         // slots 4..7
    for (int t = 0; t < S_TGT; ++t) {
        k_gates_ks<<<dim3(96, 2, 4), 256, 0, stream>>>(
            dec_emb, amax + (size_t)t * BB, hb1, dWih, dWhh, gi_p, gh_p);
        k_update_f<<<512, 256, 0, stream>>>(gi_p, 4, dbih, gh_p, 4, dbhh, hb1);
        k_logits_amax<<<250, 512, 0, stream>>>(
            hb1, outW, outb, out + (size_t)t * BB * VOUT,
            amax + (size_t)(t + 1) * BB);
    }
}